// Round 6
// baseline (281.496 us; speedup 1.0000x reference)
//
#include <hip/hip_runtime.h>

// ArcMarginLoss fused: normalize -> bf16 MFMA GEMM + fixed-max softmax -> NLL mean.
// N=8192, D=512, C=32000, scale=16, margin=0.2.
// R6: halve LDS B-read traffic — each wave holds TWO A-tiles (af[2][32], 256 VGPR,
// full K=512 resident) and issues 2 MFMAs per B ds_read. BM=256, grid=256 = 1
// block/CU exact. launch_bounds(256,1) so ~340 VGPRs allocate spill-free.

typedef __attribute__((ext_vector_type(4))) float f32x4;
typedef __attribute__((ext_vector_type(16))) float f32x16;
typedef __attribute__((ext_vector_type(8))) short s16x8;

constexpr int N = 8192, D = 512, C = 32000;
constexpr int BM = 256;            // rows per block (4 waves x 64 rows)
constexpr int BN = 32;             // cols per chunk (one transposed 32-col group)
constexpr int NSPLIT = 8;          // column splits of C
constexpr int CPS = C / NSPLIT;    // 4000 cols per split
constexpr int NCHUNK = CPS / BN;   // 125 chunks (exact)
constexpr int KT = D / 16;         // 32 k-tiles of 16
constexpr float SCL = 16.0f;
constexpr float LOG2E = 1.4426950408889634f;
constexpr float S2 = SCL * LOG2E;
constexpr float COSM = 0.98006657784124163f;  // cos(0.2)
constexpr float SINM = 0.19866933079506122f;  // sin(0.2)
constexpr float EPSC = 1e-7f;

__device__ __forceinline__ unsigned short f2bf(float f) {
  unsigned u = __float_as_uint(f);
  return (unsigned short)((u + 0x7fffu + ((u >> 16) & 1u)) >> 16);  // RNE
}

__device__ __forceinline__ void gload_lds16(const void* g, void* l) {
  __builtin_amdgcn_global_load_lds(
      (const __attribute__((address_space(1))) void*)g,
      (__attribute__((address_space(3))) void*)l, 16, 0, 0);
}

// x: one wave per row, row-major bf16 out.
__global__ void k_norm_x(const float* __restrict__ in, unsigned short* __restrict__ out) {
  int w = (blockIdx.x << 2) + (threadIdx.x >> 6);
  int lane = threadIdx.x & 63;
  const float* row = in + (size_t)w * D;
  f32x4 a = *(const f32x4*)(row + lane * 8);
  f32x4 b = *(const f32x4*)(row + lane * 8 + 4);
  float ss = a.x*a.x + a.y*a.y + a.z*a.z + a.w*a.w
           + b.x*b.x + b.y*b.y + b.z*b.z + b.w*b.w;
  #pragma unroll
  for (int m = 1; m <= 32; m <<= 1) ss += __shfl_xor(ss, m, 64);
  float sc = 1.0f / fmaxf(sqrtf(ss), 1e-12f);
  uint4 pk;
  pk.x = (unsigned)f2bf(a.x*sc) | ((unsigned)f2bf(a.y*sc) << 16);
  pk.y = (unsigned)f2bf(a.z*sc) | ((unsigned)f2bf(a.w*sc) << 16);
  pk.z = (unsigned)f2bf(b.x*sc) | ((unsigned)f2bf(b.y*sc) << 16);
  pk.w = (unsigned)f2bf(b.z*sc) | ((unsigned)f2bf(b.w*sc) << 16);
  *(uint4*)(out + (size_t)w * D + lane * 8) = pk;
}

// w: normalize 32 rows per block, emit transposed 32-col group layout:
// uint4 slot [kt*64 + h*32 + col] = w[g*32+col][kt*16 + h*8 .. +8]  (h in {0,1}).
__global__ void k_normw_t(const float* __restrict__ in, uint4* __restrict__ wt) {
  __shared__ uint4 lbuf[2048];  // 32 KB
  const int tid = threadIdx.x, wv = tid >> 6, lane = tid & 63;
  const int gidx = blockIdx.x;
  #pragma unroll
  for (int t = 0; t < 8; ++t) {
    int rl = t * 4 + wv;  // 0..31
    const float* row = in + ((size_t)gidx * 32 + rl) * D;
    f32x4 a = *(const f32x4*)(row + lane * 8);
    f32x4 b = *(const f32x4*)(row + lane * 8 + 4);
    float ss = a.x*a.x + a.y*a.y + a.z*a.z + a.w*a.w
             + b.x*b.x + b.y*b.y + b.z*b.z + b.w*b.w;
    #pragma unroll
    for (int m = 1; m <= 32; m <<= 1) ss += __shfl_xor(ss, m, 64);
    float sc = 1.0f / fmaxf(sqrtf(ss), 1e-12f);
    uint4 pk;
    pk.x = (unsigned)f2bf(a.x*sc) | ((unsigned)f2bf(a.y*sc) << 16);
    pk.y = (unsigned)f2bf(a.z*sc) | ((unsigned)f2bf(a.w*sc) << 16);
    pk.z = (unsigned)f2bf(b.x*sc) | ((unsigned)f2bf(b.y*sc) << 16);
    pk.w = (unsigned)f2bf(b.z*sc) | ((unsigned)f2bf(b.w*sc) << 16);
    int ba = ((lane >> 1) * 64 + (lane & 1) * 32 + rl) * 16;
    ba ^= ((ba >> 10) & 7) << 4;  // spread transpose-write across banks
    *(uint4*)((char*)lbuf + ba) = pk;
  }
  __syncthreads();
  char* outp = (char*)(wt + (size_t)gidx * 2048);
  #pragma unroll
  for (int i = 0; i < 8; ++i) {
    int ba = i * 4096 + tid * 16;
    int sb = ba ^ (((ba >> 10) & 7) << 4);
    *(uint4*)(outp + ba) = *(const uint4*)((const char*)lbuf + sb);
  }
}

// Label-column cosine in f32 (one wave per row) -> coslab[N].
__global__ void k_lab(const float* __restrict__ x, const float* __restrict__ w,
                      const int* __restrict__ labels, float* __restrict__ coslab) {
  int r = (blockIdx.x << 2) + (threadIdx.x >> 6);
  int lane = threadIdx.x & 63;
  const float* xr = x + (size_t)r * D;
  const float* wr = w + (size_t)labels[r] * D;
  f32x4 a = *(const f32x4*)(xr + lane * 8);
  f32x4 b = *(const f32x4*)(xr + lane * 8 + 4);
  f32x4 p = *(const f32x4*)(wr + lane * 8);
  f32x4 q = *(const f32x4*)(wr + lane * 8 + 4);
  float xx = a.x*a.x + a.y*a.y + a.z*a.z + a.w*a.w + b.x*b.x + b.y*b.y + b.z*b.z + b.w*b.w;
  float ww = p.x*p.x + p.y*p.y + p.z*p.z + p.w*p.w + q.x*q.x + q.y*q.y + q.z*q.z + q.w*q.w;
  float xw = a.x*p.x + a.y*p.y + a.z*p.z + a.w*p.w + b.x*q.x + b.y*q.y + b.z*q.z + b.w*q.w;
  #pragma unroll
  for (int m = 1; m <= 32; m <<= 1) {
    xx += __shfl_xor(xx, m, 64);
    ww += __shfl_xor(ww, m, 64);
    xw += __shfl_xor(xw, m, 64);
  }
  if (lane == 0)
    coslab[r] = xw / (fmaxf(sqrtf(xx), 1e-12f) * fmaxf(sqrtf(ww), 1e-12f));
}

// Fused GEMM (32x32x16 MFMA, 2 A-tiles/wave) + fixed-max softmax partials.
__global__ __launch_bounds__(256, 1) void k_fused(
    const unsigned short* __restrict__ xn, const char* __restrict__ wt,
    float* __restrict__ pS) {
  __shared__ __align__(16) char wbuf[2][BN * D * 2];  // 2 x 32KB
  const int tid = threadIdx.x;
  const int wv = tid >> 6, lane = tid & 63;
  const int half = lane >> 5, lr = lane & 31;
  const int bid = blockIdx.x;
  const int sp = bid & 7;               // XCD x owns split x (round-robin dispatch)
  const int rb = bid >> 3;              // 0..31
  const int row0 = rb * BM + wv * 64;   // this wave's 64 rows

  // Two A-tiles fully K-resident: af[t][kt] elem j = x[row0+t*32+lr][kt*16+half*8+j].
  // 256 VGPRs. Same (half,j)->k convention as B, so any HW K-permutation cancels.
  s16x8 af[2][KT];
  #pragma unroll
  for (int t = 0; t < 2; ++t) {
    const unsigned short* xr = xn + (size_t)(row0 + t * 32 + lr) * D + half * 8;
    #pragma unroll
    for (int kt = 0; kt < KT; ++kt) af[t][kt] = *(const s16x8*)(xr + kt * 16);
  }

  float accS[2][16];
  #pragma unroll
  for (int t = 0; t < 2; ++t)
    #pragma unroll
    for (int i = 0; i < 16; ++i) accS[t][i] = 0.0f;

  const char* gbase = wt + (size_t)(sp * NCHUNK) * 32768;
  auto stage = [&](int buf, int ch) {
    const char* src = gbase + (size_t)ch * 32768;
    #pragma unroll
    for (int i = 0; i < 8; ++i) {
      int off = i * 4096 + wv * 1024;   // wave-uniform LDS offset
      gload_lds16(src + off + lane * 16, &wbuf[buf][0] + off);
    }
  };

  stage(0, 0);
  __syncthreads();
  int cur = 0;
  for (int ch = 0; ch < NCHUNK; ++ch) {
    if (ch + 1 < NCHUNK) stage(cur ^ 1, ch + 1);

    f32x16 acc0 = (f32x16)0.0f, acc1 = (f32x16)0.0f;
    const char* lb = &wbuf[cur][0] + lane * 16;
    #pragma unroll
    for (int kt = 0; kt < KT; ++kt) {
      s16x8 b = *(const s16x8*)(lb + kt * 1024);  // 1 read feeds 2 MFMAs
      acc0 = __builtin_amdgcn_mfma_f32_32x32x16_bf16(af[0][kt], b, acc0, 0, 0, 0);
      acc1 = __builtin_amdgcn_mfma_f32_32x32x16_bf16(af[1][kt], b, acc1, 0, 0, 0);
    }

    __syncthreads();  // epilogue below is LDS-free; overlaps next chunk's reads

    #pragma unroll
    for (int i = 0; i < 16; ++i) {
      accS[0][i] += __builtin_amdgcn_exp2f(fmaf(acc0[i], S2, -S2));
      accS[1][i] += __builtin_amdgcn_exp2f(fmaf(acc1[i], S2, -S2));
    }
    cur ^= 1;
  }

  // Reduce over the 32 col-lanes within each half; write per-(row,split) sums.
  #pragma unroll
  for (int t = 0; t < 2; ++t)
    #pragma unroll
    for (int i = 0; i < 16; ++i) {
      float S = accS[t][i];
      #pragma unroll
      for (int m = 1; m <= 16; m <<= 1) S += __shfl_xor(S, m, 64);
      if (lr == 0) {
        int rl = (i & 3) + 8 * (i >> 2) + 4 * half;  // verified 32x32 C/D row map
        pS[(size_t)sp * N + row0 + t * 32 + rl] = S;
      }
    }
}

// Merge: S over splits; swap plain label term for margin term; NLL mean.
__global__ void k_merge(const float* __restrict__ pS, const float* __restrict__ coslab,
                        float* __restrict__ out) {
  int row = blockIdx.x * 256 + threadIdx.x;
  float S = 0.0f;
  #pragma unroll
  for (int s = 0; s < NSPLIT; ++s) S += pS[(size_t)s * N + row];
  float cl = coslab[row];
  float zp = SCL * cl;
  float ccl = fminf(fmaxf(cl, -1.0f + EPSC), 1.0f - EPSC);
  float zm = SCL * (ccl * COSM - sqrtf(1.0f - ccl * ccl) * SINM);
  float denom = S - __expf(zp - SCL) + __expf(zm - SCL);
  float nll = SCL + logf(denom) - zm;
  #pragma unroll
  for (int m = 1; m <= 32; m <<= 1) nll += __shfl_xor(nll, m, 64);
  __shared__ float part[4];
  if ((threadIdx.x & 63) == 0) part[threadIdx.x >> 6] = nll;
  __syncthreads();
  if (threadIdx.x == 0)
    atomicAdd(out, (part[0] + part[1] + part[2] + part[3]) * (1.0f / N));
}

__global__ void k_zero(float* out) { *out = 0.0f; }

extern "C" void kernel_launch(void* const* d_in, const int* in_sizes, int n_in,
                              void* d_out, int out_size, void* d_ws, size_t ws_size,
                              hipStream_t stream) {
  const float* x = (const float*)d_in[0];
  const float* w = (const float*)d_in[1];
  const int* labels = (const int*)d_in[2];
  float* out = (float*)d_out;

  // ws: xn bf16 [N*D] | wt bf16-transposed [C*D] | pS f32 [NSPLIT*N] | coslab f32 [N]
  unsigned short* xn = (unsigned short*)d_ws;
  char* wt = (char*)(xn + (size_t)N * D);
  float* pS = (float*)(wt + (size_t)C * D * 2);
  float* coslab = pS + (size_t)NSPLIT * N;

  hipLaunchKernelGGL(k_zero, dim3(1), dim3(1), 0, stream, out);
  hipLaunchKernelGGL(k_norm_x, dim3(N / 4), dim3(256), 0, stream, x, xn);
  hipLaunchKernelGGL(k_normw_t, dim3(C / 32), dim3(256), 0, stream, w, (uint4*)wt);
  hipLaunchKernelGGL(k_lab, dim3(N / 4), dim3(256), 0, stream, x, w, labels, coslab);
  hipLaunchKernelGGL(k_fused, dim3(32 * NSPLIT), dim3(256), 0, stream, xn, wt, pS);
  hipLaunchKernelGGL(k_merge, dim3(N / 256), dim3(256), 0, stream, pS, coslab, out);
}

// Round 7
// 214.336 us; speedup vs baseline: 1.3133x; 1.3133x over previous
//
#include <hip/hip_runtime.h>

// ArcMarginLoss fused: normalize -> fp8 MFMA GEMM + fixed-max softmax -> NLL mean.
// N=8192, D=512, C=32000, scale=16, margin=0.2.
// R7: fp8 e4m3 GEMM (16x16x32_fp8_fp8, bf16-rate but half the bytes). 4 A-tiles
// per wave fully K-resident in 128 VGPRs -> each B ds_read feeds 4 MFMAs
// (15.6 mB/FLOP, half of R3/R5's 31). 2 blocks/CU (grid 512), 2 waves/SIMD.
// Label+margin path stays f32 (k_lab), so fp8 only perturbs the softmax denom.

typedef __attribute__((ext_vector_type(4))) float f32x4;

constexpr int N = 8192, D = 512, C = 32000;
constexpr int BM = 256;            // rows per block (4 waves x 4 tiles x 16 rows)
constexpr int GRP = 16;            // cols per chunk
constexpr int NSPLIT = 16;         // column splits of C
constexpr int CPS = C / NSPLIT;    // 2000 cols per split
constexpr int NCHUNK = CPS / GRP;  // 125 chunks (exact)
constexpr int KT = D / 32;         // 16 k-tiles of K=32
constexpr float SCL = 16.0f;
constexpr float LOG2E = 1.4426950408889634f;
constexpr float S2 = SCL * LOG2E;
constexpr float COSM = 0.98006657784124163f;  // cos(0.2)
constexpr float SINM = 0.19866933079506122f;  // sin(0.2)
constexpr float EPSC = 1e-7f;

__device__ __forceinline__ void gload_lds16(const void* g, void* l) {
  __builtin_amdgcn_global_load_lds(
      (const __attribute__((address_space(1))) void*)g,
      (__attribute__((address_space(3))) void*)l, 16, 0, 0);
}

// Pack 8 scaled floats -> 8 fp8 e4m3 bytes (two i32 words), hw RNE+sat.
__device__ __forceinline__ void pack8_fp8(const float* f, float sc, int& lo, int& hi) {
  lo = __builtin_amdgcn_cvt_pk_fp8_f32(f[0] * sc, f[1] * sc, 0, 0);
  lo = __builtin_amdgcn_cvt_pk_fp8_f32(f[2] * sc, f[3] * sc, lo, 1);
  hi = __builtin_amdgcn_cvt_pk_fp8_f32(f[4] * sc, f[5] * sc, 0, 0);
  hi = __builtin_amdgcn_cvt_pk_fp8_f32(f[6] * sc, f[7] * sc, hi, 1);
}

// x: one wave per row, L2-normalize, emit row-major fp8 (8 B/lane).
__global__ void k_norm_x(const float* __restrict__ in, char* __restrict__ out) {
  int w = (blockIdx.x << 2) + (threadIdx.x >> 6);
  int lane = threadIdx.x & 63;
  const float* row = in + (size_t)w * D;
  float f[8];
  *(f32x4*)&f[0] = *(const f32x4*)(row + lane * 8);
  *(f32x4*)&f[4] = *(const f32x4*)(row + lane * 8 + 4);
  float ss = 0.f;
  #pragma unroll
  for (int i = 0; i < 8; ++i) ss += f[i] * f[i];
  #pragma unroll
  for (int m = 1; m <= 32; m <<= 1) ss += __shfl_xor(ss, m, 64);
  float sc = 1.0f / fmaxf(sqrtf(ss), 1e-12f);
  int lo, hi;
  pack8_fp8(f, sc, lo, hi);
  int2 pk; pk.x = lo; pk.y = hi;
  *(int2*)(out + (size_t)w * D + lane * 8) = pk;
}

// w: one block per 16-col group; normalize 16 rows, emit fused-ready layout:
// 8KB/group; byte addr = (kt>>1)*1024 + (g*16 + col)*16 + (kt&1)*8 holds
// w[col][kt*32 + g*8 .. +8] as fp8. Fused stage is a linear 8KB copy.
__global__ void k_normw_t(const float* __restrict__ in, char* __restrict__ wt) {
  __shared__ __align__(16) char lbuf[8192];
  const int tid = threadIdx.x, wv = tid >> 6, L = tid & 63;
  const int gidx = blockIdx.x;
  #pragma unroll
  for (int t = 0; t < 4; ++t) {
    int rl = t * 4 + wv;  // 0..15 (col within group)
    const float* row = in + ((size_t)gidx * 16 + rl) * D;
    float f[8];
    *(f32x4*)&f[0] = *(const f32x4*)(row + L * 8);
    *(f32x4*)&f[4] = *(const f32x4*)(row + L * 8 + 4);
    float ss = 0.f;
    #pragma unroll
    for (int i = 0; i < 8; ++i) ss += f[i] * f[i];
    #pragma unroll
    for (int m = 1; m <= 32; m <<= 1) ss += __shfl_xor(ss, m, 64);
    float sc = 1.0f / fmaxf(sqrtf(ss), 1e-12f);
    int lo, hi;
    pack8_fp8(f, sc, lo, hi);
    // lane L covers k in [8L, 8L+8): kt = L>>2, g = L&3, kp = L>>3, odd = (L>>2)&1
    int addr = (L >> 3) * 1024 + ((L & 3) * 16 + rl) * 16 + ((L >> 2) & 1) * 8;
    long pk = ((long)(unsigned)hi << 32) | (unsigned)lo;
    *(long*)(lbuf + addr) = pk;
  }
  __syncthreads();
  char* outp = wt + (size_t)gidx * 8192;
  #pragma unroll
  for (int i = 0; i < 2; ++i)
    *(uint4*)(outp + i * 4096 + tid * 16) = *(const uint4*)(lbuf + i * 4096 + tid * 16);
}

// Label-column cosine in f32 (one wave per row) -> coslab[N].
__global__ void k_lab(const float* __restrict__ x, const float* __restrict__ w,
                      const int* __restrict__ labels, float* __restrict__ coslab) {
  int r = (blockIdx.x << 2) + (threadIdx.x >> 6);
  int lane = threadIdx.x & 63;
  const float* xr = x + (size_t)r * D;
  const float* wr = w + (size_t)labels[r] * D;
  f32x4 a = *(const f32x4*)(xr + lane * 8);
  f32x4 b = *(const f32x4*)(xr + lane * 8 + 4);
  f32x4 p = *(const f32x4*)(wr + lane * 8);
  f32x4 q = *(const f32x4*)(wr + lane * 8 + 4);
  float xx = a.x*a.x + a.y*a.y + a.z*a.z + a.w*a.w + b.x*b.x + b.y*b.y + b.z*b.z + b.w*b.w;
  float ww = p.x*p.x + p.y*p.y + p.z*p.z + p.w*p.w + q.x*q.x + q.y*q.y + q.z*q.z + q.w*q.w;
  float xw = a.x*p.x + a.y*p.y + a.z*p.z + a.w*p.w + b.x*q.x + b.y*q.y + b.z*q.z + b.w*q.w;
  #pragma unroll
  for (int m = 1; m <= 32; m <<= 1) {
    xx += __shfl_xor(xx, m, 64);
    ww += __shfl_xor(ww, m, 64);
    xw += __shfl_xor(xw, m, 64);
  }
  if (lane == 0)
    coslab[r] = xw / (fmaxf(sqrtf(xx), 1e-12f) * fmaxf(sqrtf(ww), 1e-12f));
}

// Fused fp8 GEMM (4 A-tiles/wave, r=4 B-reuse) + fixed-max softmax partials.
__global__ __launch_bounds__(256, 2) void k_fused(
    const char* __restrict__ xn8, const char* __restrict__ wt,
    float* __restrict__ pS) {
  __shared__ __align__(16) char wbuf[2][GRP * D];  // 2 x 8KB
  const int tid = threadIdx.x;
  const int wv = tid >> 6, lane = tid & 63;
  const int g = lane >> 4, c = lane & 15;
  const int bid = blockIdx.x;
  const int logical = (bid & 7) * 64 + (bid >> 3);  // 512 = 8*64 XCD swizzle
  const int sp = logical >> 5;          // 0..15 (2 splits per XCD, 2MB in L2)
  const int rb = logical & 31;          // 0..31
  const int row0 = rb * BM + wv * 64;   // this wave's 64 rows (4 tiles of 16)

  // 4 A-tiles fully K-resident as fp8: af[t][kt] = x[row0+t*16+c][kt*32+g*8 ..+8].
  // 128 VGPRs. Identical k-slot packing as B -> HW K-permutation cancels.
  long af[4][KT];
  #pragma unroll
  for (int t = 0; t < 4; ++t) {
    const char* xr = xn8 + (size_t)(row0 + t * 16 + c) * D + g * 8;
    #pragma unroll
    for (int kt = 0; kt < KT; ++kt) af[t][kt] = *(const long*)(xr + kt * 32);
  }

  float accS[4][4];
  #pragma unroll
  for (int t = 0; t < 4; ++t)
    #pragma unroll
    for (int r = 0; r < 4; ++r) accS[t][r] = 0.0f;

  const char* gbase = wt + (size_t)(sp * NCHUNK) * 8192;
  auto stage = [&](int buf, int ch) {
    const char* src = gbase + (size_t)ch * 8192;
    #pragma unroll
    for (int i = 0; i < 2; ++i) {
      int ou = i * 4096 + wv * 1024;    // wave-uniform LDS offset
      gload_lds16(src + ou + lane * 16, &wbuf[buf][0] + ou);
    }
  };

  stage(0, 0);
  __syncthreads();
  int cur = 0;
  for (int ch = 0; ch < NCHUNK; ++ch) {
    if (ch + 1 < NCHUNK) stage(cur ^ 1, ch + 1);

    f32x4 acc[4];
    #pragma unroll
    for (int t = 0; t < 4; ++t) acc[t] = (f32x4)0.0f;

    const char* lb = &wbuf[cur][0] + lane * 16;
    #pragma unroll
    for (int kp = 0; kp < 8; ++kp) {  // 16B read = kt pair; each frag feeds 4 MFMAs
      long2 bb = *(const long2*)(lb + kp * 1024);
      #pragma unroll
      for (int t = 0; t < 4; ++t)
        acc[t] = __builtin_amdgcn_mfma_f32_16x16x32_fp8_fp8(
            af[t][2 * kp], bb.x, acc[t], 0, 0, 0);
      #pragma unroll
      for (int t = 0; t < 4; ++t)
        acc[t] = __builtin_amdgcn_mfma_f32_16x16x32_fp8_fp8(
            af[t][2 * kp + 1], bb.y, acc[t], 0, 0, 0);
    }

    __syncthreads();  // LDS-free epilogue below overlaps next chunk's ds_reads

    #pragma unroll
    for (int t = 0; t < 4; ++t)
      #pragma unroll
      for (int r = 0; r < 4; ++r)
        accS[t][r] += __builtin_amdgcn_exp2f(fmaf(acc[t][r], S2, -S2));
    cur ^= 1;
  }

  // Sum over the 16 col-lanes of each group; write per-(row,split) partials.
  #pragma unroll
  for (int t = 0; t < 4; ++t)
    #pragma unroll
    for (int r = 0; r < 4; ++r) {
      float S = accS[t][r];
      #pragma unroll
      for (int m = 1; m <= 8; m <<= 1) S += __shfl_xor(S, m, 64);
      if (c == 0)
        pS[(size_t)sp * N + row0 + t * 16 + g * 4 + r] = S;
    }
}

// Merge: S over splits; swap plain label term for f32 margin term; NLL mean.
__global__ void k_merge(const float* __restrict__ pS, const float* __restrict__ coslab,
                        float* __restrict__ out) {
  int row = blockIdx.x * 256 + threadIdx.x;
  float S = 0.0f;
  #pragma unroll
  for (int s = 0; s < NSPLIT; ++s) S += pS[(size_t)s * N + row];
  float cl = coslab[row];
  float zp = SCL * cl;
  float ccl = fminf(fmaxf(cl, -1.0f + EPSC), 1.0f - EPSC);
  float zm = SCL * (ccl * COSM - sqrtf(1.0f - ccl * ccl) * SINM);
  float denom = S - __expf(zp - SCL) + __expf(zm - SCL);
  float nll = SCL + logf(denom) - zm;
  #pragma unroll
  for (int m = 1; m <= 32; m <<= 1) nll += __shfl_xor(nll, m, 64);
  __shared__ float part[4];
  if ((threadIdx.x & 63) == 0) part[threadIdx.x >> 6] = nll;
  __syncthreads();
  if (threadIdx.x == 0)
    atomicAdd(out, (part[0] + part[1] + part[2] + part[3]) * (1.0f / N));
}

__global__ void k_zero(float* out) { *out = 0.0f; }

extern "C" void kernel_launch(void* const* d_in, const int* in_sizes, int n_in,
                              void* d_out, int out_size, void* d_ws, size_t ws_size,
                              hipStream_t stream) {
  const float* x = (const float*)d_in[0];
  const float* w = (const float*)d_in[1];
  const int* labels = (const int*)d_in[2];
  float* out = (float*)d_out;

  // ws: xn8 fp8 [N*D] | wt fp8-grouped [C*D] | pS f32 [NSPLIT*N] | coslab f32 [N]
  char* xn8 = (char*)d_ws;
  char* wt = xn8 + (size_t)N * D;
  float* pS = (float*)(wt + (size_t)C * D);
  float* coslab = pS + (size_t)NSPLIT * N;

  hipLaunchKernelGGL(k_zero, dim3(1), dim3(1), 0, stream, out);
  hipLaunchKernelGGL(k_norm_x, dim3(N / 4), dim3(256), 0, stream, x, xn8);
  hipLaunchKernelGGL(k_normw_t, dim3(C / 16), dim3(256), 0, stream, w, wt);
  hipLaunchKernelGGL(k_lab, dim3(N / 4), dim3(256), 0, stream, x, w, labels, coslab);
  hipLaunchKernelGGL(k_fused, dim3(32 * NSPLIT), dim3(256), 0, stream, xn8, wt, pS);
  hipLaunchKernelGGL(k_merge, dim3(N / 256), dim3(256), 0, stream, pS, coslab, out);
}

// Round 8
// 150.846 us; speedup vs baseline: 1.8661x; 1.4209x over previous
//
#include <hip/hip_runtime.h>

// ArcMarginLoss fused: normalize -> MX-fp8 MFMA GEMM + fixed-max softmax -> NLL mean.
// N=8192, D=512, C=32000, scale=16, margin=0.2.
// R8: mfma_scale_f32_16x16x128_f8f6f4 with unit scales (E8M0 127) — ~4661 TF vs
// 2075 for non-scaled fp8 (the only path to fp8 peak). Same products as R7,
// K=128/instruction. Structure unchanged: 4 A-tiles/wave K-resident (128 regs),
// B-reuse 4, 2 blocks/CU, grid 512, conflict-free lane-contiguous LDS reads.

typedef __attribute__((ext_vector_type(4))) float f32x4;
typedef __attribute__((ext_vector_type(8))) int i32x8;

constexpr int N = 8192, D = 512, C = 32000;
constexpr int BM = 256;            // rows per block (4 waves x 4 tiles x 16 rows)
constexpr int GRP = 16;            // cols per chunk
constexpr int NSPLIT = 16;         // column splits of C
constexpr int CPS = C / NSPLIT;    // 2000 cols per split
constexpr int NCHUNK = CPS / GRP;  // 125 chunks (exact)
constexpr int KS = D / 128;        // 4 k-steps of K=128
constexpr float SCL = 16.0f;
constexpr float LOG2E = 1.4426950408889634f;
constexpr float S2 = SCL * LOG2E;
constexpr float COSM = 0.98006657784124163f;  // cos(0.2)
constexpr float SINM = 0.19866933079506122f;  // sin(0.2)
constexpr float EPSC = 1e-7f;
constexpr int SC1 = 0x7F7F7F7F;    // E8M0 scale bytes = 127 -> 2^0 = 1.0

__device__ __forceinline__ void gload_lds16(const void* g, void* l) {
  __builtin_amdgcn_global_load_lds(
      (const __attribute__((address_space(1))) void*)g,
      (__attribute__((address_space(3))) void*)l, 16, 0, 0);
}

// Pack 8 scaled floats -> 8 fp8 e4m3 bytes (two i32 words), hw RNE+sat.
__device__ __forceinline__ void pack8_fp8(const float* f, float sc, int& lo, int& hi) {
  lo = __builtin_amdgcn_cvt_pk_fp8_f32(f[0] * sc, f[1] * sc, 0, 0);
  lo = __builtin_amdgcn_cvt_pk_fp8_f32(f[2] * sc, f[3] * sc, lo, 1);
  hi = __builtin_amdgcn_cvt_pk_fp8_f32(f[4] * sc, f[5] * sc, 0, 0);
  hi = __builtin_amdgcn_cvt_pk_fp8_f32(f[6] * sc, f[7] * sc, hi, 1);
}

// x: one wave per row, L2-normalize, emit row-major fp8 (8 B/lane).
__global__ void k_norm_x(const float* __restrict__ in, char* __restrict__ out) {
  int w = (blockIdx.x << 2) + (threadIdx.x >> 6);
  int lane = threadIdx.x & 63;
  const float* row = in + (size_t)w * D;
  float f[8];
  *(f32x4*)&f[0] = *(const f32x4*)(row + lane * 8);
  *(f32x4*)&f[4] = *(const f32x4*)(row + lane * 8 + 4);
  float ss = 0.f;
  #pragma unroll
  for (int i = 0; i < 8; ++i) ss += f[i] * f[i];
  #pragma unroll
  for (int m = 1; m <= 32; m <<= 1) ss += __shfl_xor(ss, m, 64);
  float sc = 1.0f / fmaxf(sqrtf(ss), 1e-12f);
  int lo, hi;
  pack8_fp8(f, sc, lo, hi);
  int2 pk; pk.x = lo; pk.y = hi;
  *(int2*)(out + (size_t)w * D + lane * 8) = pk;
}

// w: one block per 16-col group; normalize 16 rows, emit fused-ready layout.
// Per 8KB group: byte addr = ks*2048 + h*1024 + (g*16 + col)*16 + j holds
// w[col][ks*128 + g*32 + h*16 + j] (j in 0..15). Lane-contiguous for ds_read.
__global__ void k_normw_t(const float* __restrict__ in, char* __restrict__ wt) {
  __shared__ __align__(16) char lbuf[8192];
  const int tid = threadIdx.x, wv = tid >> 6, L = tid & 63;
  const int gidx = blockIdx.x;
  #pragma unroll
  for (int t = 0; t < 4; ++t) {
    int rl = t * 4 + wv;  // 0..15 (col within group)
    const float* row = in + ((size_t)gidx * 16 + rl) * D;
    float f[8];
    *(f32x4*)&f[0] = *(const f32x4*)(row + L * 8);
    *(f32x4*)&f[4] = *(const f32x4*)(row + L * 8 + 4);
    float ss = 0.f;
    #pragma unroll
    for (int i = 0; i < 8; ++i) ss += f[i] * f[i];
    #pragma unroll
    for (int m = 1; m <= 32; m <<= 1) ss += __shfl_xor(ss, m, 64);
    float sc = 1.0f / fmaxf(sqrtf(ss), 1e-12f);
    int lo, hi;
    pack8_fp8(f, sc, lo, hi);
    // lane L covers k in [8L,8L+8): ks=L>>4, g=(L>>2)&3, h=(L>>1)&1, j=(L&1)*8
    int addr = (L >> 4) * 2048 + ((L >> 1) & 1) * 1024
             + (((L >> 2) & 3) * 16 + rl) * 16 + (L & 1) * 8;
    addr ^= ((addr >> 8) & 7) << 4;  // involutive bank-spread for the write
    long pk = ((long)(unsigned)hi << 32) | (unsigned)lo;
    *(long*)(lbuf + addr) = pk;
  }
  __syncthreads();
  char* outp = wt + (size_t)gidx * 8192;
  #pragma unroll
  for (int i = 0; i < 2; ++i) {
    int la = i * 4096 + tid * 16;
    int sla = la ^ (((la >> 8) & 7) << 4);  // undo the write swizzle
    *(uint4*)(outp + la) = *(const uint4*)(lbuf + sla);
  }
}

// Label-column cosine in f32 (one wave per row) -> coslab[N].
__global__ void k_lab(const float* __restrict__ x, const float* __restrict__ w,
                      const int* __restrict__ labels, float* __restrict__ coslab) {
  int r = (blockIdx.x << 2) + (threadIdx.x >> 6);
  int lane = threadIdx.x & 63;
  const float* xr = x + (size_t)r * D;
  const float* wr = w + (size_t)labels[r] * D;
  f32x4 a = *(const f32x4*)(xr + lane * 8);
  f32x4 b = *(const f32x4*)(xr + lane * 8 + 4);
  f32x4 p = *(const f32x4*)(wr + lane * 8);
  f32x4 q = *(const f32x4*)(wr + lane * 8 + 4);
  float xx = a.x*a.x + a.y*a.y + a.z*a.z + a.w*a.w + b.x*b.x + b.y*b.y + b.z*b.z + b.w*b.w;
  float ww = p.x*p.x + p.y*p.y + p.z*p.z + p.w*p.w + q.x*q.x + q.y*q.y + q.z*q.z + q.w*q.w;
  float xw = a.x*p.x + a.y*p.y + a.z*p.z + a.w*p.w + b.x*q.x + b.y*q.y + b.z*q.z + b.w*q.w;
  #pragma unroll
  for (int m = 1; m <= 32; m <<= 1) {
    xx += __shfl_xor(xx, m, 64);
    ww += __shfl_xor(ww, m, 64);
    xw += __shfl_xor(xw, m, 64);
  }
  if (lane == 0)
    coslab[r] = xw / (fmaxf(sqrtf(xx), 1e-12f) * fmaxf(sqrtf(ww), 1e-12f));
}

// Fused MX-fp8 GEMM (4 A-tiles/wave, B-reuse 4) + fixed-max softmax partials.
__global__ __launch_bounds__(256, 2) void k_fused(
    const char* __restrict__ xn8, const char* __restrict__ wt,
    float* __restrict__ pS) {
  __shared__ __align__(16) char wbuf[2][GRP * D];  // 2 x 8KB
  const int tid = threadIdx.x;
  const int wv = tid >> 6, lane = tid & 63;
  const int g = lane >> 4, c = lane & 15;
  const int bid = blockIdx.x;
  const int logical = (bid & 7) * 64 + (bid >> 3);  // 512 = 8*64 XCD swizzle
  const int sp = logical >> 5;          // 0..15 (2 splits per XCD)
  const int rb = logical & 31;          // 0..31
  const int row0 = rb * BM + wv * 64;   // this wave's 64 rows (4 tiles of 16)

  // 4 A-tiles fully K-resident: af[t][ks] = x[row0+t*16+c][ks*128+g*32 .. +32]
  // as 8 dwords (contiguous k ascending). 128 regs. Same per-lane packing as B.
  i32x8 af[4][KS];
  #pragma unroll
  for (int t = 0; t < 4; ++t) {
    const char* xr = xn8 + (size_t)(row0 + t * 16 + c) * D + g * 32;
    #pragma unroll
    for (int ks = 0; ks < KS; ++ks) af[t][ks] = *(const i32x8*)(xr + ks * 128);
  }

  float accS[4][4];
  #pragma unroll
  for (int t = 0; t < 4; ++t)
    #pragma unroll
    for (int r = 0; r < 4; ++r) accS[t][r] = 0.0f;

  const char* gbase = wt + (size_t)(sp * NCHUNK) * 8192;
  auto stage = [&](int buf, int ch) {
    const char* src = gbase + (size_t)ch * 8192;
    #pragma unroll
    for (int i = 0; i < 2; ++i) {
      int ou = i * 4096 + wv * 1024;    // wave-uniform LDS offset
      gload_lds16(src + ou + lane * 16, &wbuf[buf][0] + ou);
    }
  };

  stage(0, 0);
  __syncthreads();
  int cur = 0;
  for (int ch = 0; ch < NCHUNK; ++ch) {
    if (ch + 1 < NCHUNK) stage(cur ^ 1, ch + 1);

    f32x4 acc[4];
    #pragma unroll
    for (int t = 0; t < 4; ++t) acc[t] = (f32x4)0.0f;

    const char* lb = &wbuf[cur][0] + lane * 16;  // lane-contiguous: conflict-free
    #pragma unroll
    for (int ks = 0; ks < KS; ++ks) {
      uint4 b0 = *(const uint4*)(lb + ks * 2048);         // h=0 half
      uint4 b1 = *(const uint4*)(lb + ks * 2048 + 1024);  // h=1 half
      i32x8 bb;
      bb[0] = b0.x; bb[1] = b0.y; bb[2] = b0.z; bb[3] = b0.w;
      bb[4] = b1.x; bb[5] = b1.y; bb[6] = b1.z; bb[7] = b1.w;
      #pragma unroll
      for (int t = 0; t < 4; ++t)
        acc[t] = __builtin_amdgcn_mfma_scale_f32_16x16x128_f8f6f4(
            af[t][ks], bb, acc[t], 0, 0, 0, SC1, 0, SC1);
    }

    __syncthreads();  // LDS-free epilogue below overlaps next chunk's ds_reads

    #pragma unroll
    for (int t = 0; t < 4; ++t)
      #pragma unroll
      for (int r = 0; r < 4; ++r)
        accS[t][r] += __builtin_amdgcn_exp2f(fmaf(acc[t][r], S2, -S2));
    cur ^= 1;
  }

  // Sum over the 16 col-lanes of each group; write per-(row,split) partials.
  #pragma unroll
  for (int t = 0; t < 4; ++t)
    #pragma unroll
    for (int r = 0; r < 4; ++r) {
      float S = accS[t][r];
      #pragma unroll
      for (int m = 1; m <= 8; m <<= 1) S += __shfl_xor(S, m, 64);
      if (c == 0)
        pS[(size_t)sp * N + row0 + t * 16 + g * 4 + r] = S;
    }
}

// Merge: S over splits; swap plain label term for f32 margin term; NLL mean.
__global__ void k_merge(const float* __restrict__ pS, const float* __restrict__ coslab,
                        float* __restrict__ out) {
  int row = blockIdx.x * 256 + threadIdx.x;
  float S = 0.0f;
  #pragma unroll
  for (int s = 0; s < NSPLIT; ++s) S += pS[(size_t)s * N + row];
  float cl = coslab[row];
  float zp = SCL * cl;
  float ccl = fminf(fmaxf(cl, -1.0f + EPSC), 1.0f - EPSC);
  float zm = SCL * (ccl * COSM - sqrtf(1.0f - ccl * ccl) * SINM);
  float denom = S - __expf(zp - SCL) + __expf(zm - SCL);
  float nll = SCL + logf(denom) - zm;
  #pragma unroll
  for (int m = 1; m <= 32; m <<= 1) nll += __shfl_xor(nll, m, 64);
  __shared__ float part[4];
  if ((threadIdx.x & 63) == 0) part[threadIdx.x >> 6] = nll;
  __syncthreads();
  if (threadIdx.x == 0)
    atomicAdd(out, (part[0] + part[1] + part[2] + part[3]) * (1.0f / N));
}

__global__ void k_zero(float* out) { *out = 0.0f; }

extern "C" void kernel_launch(void* const* d_in, const int* in_sizes, int n_in,
                              void* d_out, int out_size, void* d_ws, size_t ws_size,
                              hipStream_t stream) {
  const float* x = (const float*)d_in[0];
  const float* w = (const float*)d_in[1];
  const int* labels = (const int*)d_in[2];
  float* out = (float*)d_out;

  // ws: xn8 fp8 [N*D] | wt fp8-grouped [C*D] | pS f32 [NSPLIT*N] | coslab f32 [N]
  char* xn8 = (char*)d_ws;
  char* wt = xn8 + (size_t)N * D;
  float* pS = (float*)(wt + (size_t)C * D);
  float* coslab = pS + (size_t)NSPLIT * N;

  hipLaunchKernelGGL(k_zero, dim3(1), dim3(1), 0, stream, out);
  hipLaunchKernelGGL(k_norm_x, dim3(N / 4), dim3(256), 0, stream, x, xn8);
  hipLaunchKernelGGL(k_normw_t, dim3(C / 16), dim3(256), 0, stream, w, wt);
  hipLaunchKernelGGL(k_lab, dim3(N / 4), dim3(256), 0, stream, x, w, labels, coslab);
  hipLaunchKernelGGL(k_fused, dim3(32 * NSPLIT), dim3(256), 0, stream, xn8, wt, pS);
  hipLaunchKernelGGL(k_merge, dim3(N / 256), dim3(256), 0, stream, pS, coslab, out);
}

// Round 9
// 140.807 us; speedup vs baseline: 1.9992x; 1.0713x over previous
//
#include <hip/hip_runtime.h>

// ArcMarginLoss fused: normalize -> MX-fp8 MFMA GEMM + fixed-max softmax -> NLL mean.
// N=8192, D=512, C=32000, scale=16, margin=0.2.
// R9: drop LDS + barriers from the K-loop. B-fragments stream directly from
// L2-resident global (2 splits x 2MB per XCD = 4MB L2) into a register double
// buffer (bA/bB). No __syncthreads, no vmcnt(0) drain -> MFMA/VALU/VMEM overlap
// freely across the 8 drifting waves/CU. Same arithmetic as R8 (bit-identical).

typedef __attribute__((ext_vector_type(4))) float f32x4;
typedef __attribute__((ext_vector_type(8))) int i32x8;

constexpr int N = 8192, D = 512, C = 32000;
constexpr int BM = 256;            // rows per block (4 waves x 4 tiles x 16 rows)
constexpr int GRP = 16;            // cols per chunk
constexpr int NSPLIT = 16;         // column splits of C
constexpr int CPS = C / NSPLIT;    // 2000 cols per split
constexpr int NCHUNK = CPS / GRP;  // 125 chunks
constexpr int KS = D / 128;        // 4 k-steps of K=128
constexpr float SCL = 16.0f;
constexpr float LOG2E = 1.4426950408889634f;
constexpr float S2 = SCL * LOG2E;
constexpr float COSM = 0.98006657784124163f;  // cos(0.2)
constexpr float SINM = 0.19866933079506122f;  // sin(0.2)
constexpr float EPSC = 1e-7f;
constexpr int SC1 = 0x7F7F7F7F;    // E8M0 scale bytes = 127 -> 2^0 = 1.0

// Pack 8 scaled floats -> 8 fp8 e4m3 bytes (two i32 words), hw RNE+sat.
__device__ __forceinline__ void pack8_fp8(const float* f, float sc, int& lo, int& hi) {
  lo = __builtin_amdgcn_cvt_pk_fp8_f32(f[0] * sc, f[1] * sc, 0, 0);
  lo = __builtin_amdgcn_cvt_pk_fp8_f32(f[2] * sc, f[3] * sc, lo, 1);
  hi = __builtin_amdgcn_cvt_pk_fp8_f32(f[4] * sc, f[5] * sc, 0, 0);
  hi = __builtin_amdgcn_cvt_pk_fp8_f32(f[6] * sc, f[7] * sc, hi, 1);
}

// x: one wave per row, L2-normalize, emit row-major fp8 (8 B/lane).
__global__ void k_norm_x(const float* __restrict__ in, char* __restrict__ out) {
  int w = (blockIdx.x << 2) + (threadIdx.x >> 6);
  int lane = threadIdx.x & 63;
  const float* row = in + (size_t)w * D;
  float f[8];
  *(f32x4*)&f[0] = *(const f32x4*)(row + lane * 8);
  *(f32x4*)&f[4] = *(const f32x4*)(row + lane * 8 + 4);
  float ss = 0.f;
  #pragma unroll
  for (int i = 0; i < 8; ++i) ss += f[i] * f[i];
  #pragma unroll
  for (int m = 1; m <= 32; m <<= 1) ss += __shfl_xor(ss, m, 64);
  float sc = 1.0f / fmaxf(sqrtf(ss), 1e-12f);
  int lo, hi;
  pack8_fp8(f, sc, lo, hi);
  int2 pk; pk.x = lo; pk.y = hi;
  *(int2*)(out + (size_t)w * D + lane * 8) = pk;
}

// w: one block per 16-col group; normalize 16 rows, emit fused-ready layout.
// Per 8KB group: byte addr = ks*2048 + (g*16 + col)*32 + j holds
// w[col][ks*128 + g*32 + j] (j in 0..31): each fused lane's 32B is contiguous.
__global__ void k_normw_t(const float* __restrict__ in, char* __restrict__ wt) {
  __shared__ __align__(16) char lbuf[8192];
  const int tid = threadIdx.x, wv = tid >> 6, L = tid & 63;
  const int gidx = blockIdx.x;
  #pragma unroll
  for (int t = 0; t < 4; ++t) {
    int rl = t * 4 + wv;  // 0..15 (col within group)
    const float* row = in + ((size_t)gidx * 16 + rl) * D;
    float f[8];
    *(f32x4*)&f[0] = *(const f32x4*)(row + L * 8);
    *(f32x4*)&f[4] = *(const f32x4*)(row + L * 8 + 4);
    float ss = 0.f;
    #pragma unroll
    for (int i = 0; i < 8; ++i) ss += f[i] * f[i];
    #pragma unroll
    for (int m = 1; m <= 32; m <<= 1) ss += __shfl_xor(ss, m, 64);
    float sc = 1.0f / fmaxf(sqrtf(ss), 1e-12f);
    int lo, hi;
    pack8_fp8(f, sc, lo, hi);
    // lane L covers k in [8L,8L+8): ks=L>>4, g=(L>>2)&3, j0=(L&3)*8
    int addr = (L >> 4) * 2048 + (((L >> 2) & 3) * 16 + rl) * 32 + (L & 3) * 8;
    long pk = ((long)(unsigned)hi << 32) | (unsigned)lo;
    *(long*)(lbuf + addr) = pk;
  }
  __syncthreads();
  char* outp = wt + (size_t)gidx * 8192;
  #pragma unroll
  for (int i = 0; i < 2; ++i)
    *(uint4*)(outp + i * 4096 + tid * 16) = *(const uint4*)(lbuf + i * 4096 + tid * 16);
}

// Label-column cosine in f32 (one wave per row) -> coslab[N].
__global__ void k_lab(const float* __restrict__ x, const float* __restrict__ w,
                      const int* __restrict__ labels, float* __restrict__ coslab) {
  int r = (blockIdx.x << 2) + (threadIdx.x >> 6);
  int lane = threadIdx.x & 63;
  const float* xr = x + (size_t)r * D;
  const float* wr = w + (size_t)labels[r] * D;
  f32x4 a = *(const f32x4*)(xr + lane * 8);
  f32x4 b = *(const f32x4*)(xr + lane * 8 + 4);
  f32x4 p = *(const f32x4*)(wr + lane * 8);
  f32x4 q = *(const f32x4*)(wr + lane * 8 + 4);
  float xx = a.x*a.x + a.y*a.y + a.z*a.z + a.w*a.w + b.x*b.x + b.y*b.y + b.z*b.z + b.w*b.w;
  float ww = p.x*p.x + p.y*p.y + p.z*p.z + p.w*p.w + q.x*q.x + q.y*q.y + q.z*q.z + q.w*q.w;
  float xw = a.x*p.x + a.y*p.y + a.z*p.z + a.w*p.w + b.x*q.x + b.y*q.y + b.z*q.z + b.w*q.w;
  #pragma unroll
  for (int m = 1; m <= 32; m <<= 1) {
    xx += __shfl_xor(xx, m, 64);
    ww += __shfl_xor(ww, m, 64);
    xw += __shfl_xor(xw, m, 64);
  }
  if (lane == 0)
    coslab[r] = xw / (fmaxf(sqrtf(xx), 1e-12f) * fmaxf(sqrtf(ww), 1e-12f));
}

// Fused MX-fp8 GEMM, barrier-free: B streams L2->registers (double-buffered).
__global__ __launch_bounds__(256, 2) void k_fused(
    const char* __restrict__ xn8, const char* __restrict__ wt,
    float* __restrict__ pS) {
  const int tid = threadIdx.x;
  const int wv = tid >> 6, lane = tid & 63;
  const int g = lane >> 4, c = lane & 15;
  const int bid = blockIdx.x;
  const int logical = (bid & 7) * 64 + (bid >> 3);  // 512 = 8*64 XCD swizzle
  const int sp = logical >> 5;          // 0..15 (2 splits per XCD = 4MB in L2)
  const int rb = logical & 31;          // 0..31
  const int row0 = rb * BM + wv * 64;   // this wave's 64 rows (4 tiles of 16)

  // 4 A-tiles fully K-resident: af[t][ks] = x[row0+t*16+c][ks*128+g*32 .. +32].
  i32x8 af[4][KS];
  #pragma unroll
  for (int t = 0; t < 4; ++t) {
    const char* xr = xn8 + (size_t)(row0 + t * 16 + c) * D + g * 32;
    #pragma unroll
    for (int ks = 0; ks < KS; ++ks) af[t][ks] = *(const i32x8*)(xr + ks * 128);
  }

  float accS[4][4];
  #pragma unroll
  for (int t = 0; t < 4; ++t)
    #pragma unroll
    for (int r = 0; r < 4; ++r) accS[t][r] = 0.0f;

  // Per-lane B base: lane's 32B fragment for (ks,chunk) at ch*8192 + ks*2048 + lane*32.
  const char* gb = wt + (size_t)(sp * NCHUNK) * 8192 + lane * 32;

  i32x8 bA[KS], bB[KS];
  #pragma unroll
  for (int ks = 0; ks < KS; ++ks) bA[ks] = *(const i32x8*)(gb + ks * 2048);
  #pragma unroll
  for (int ks = 0; ks < KS; ++ks) bB[ks] = *(const i32x8*)(gb + 8192 + ks * 2048);

  #define COMPUTE(BUF)                                                          \
    {                                                                           \
      f32x4 acc[4];                                                             \
      _Pragma("unroll") for (int t = 0; t < 4; ++t) acc[t] = (f32x4)0.0f;       \
      _Pragma("unroll") for (int ks = 0; ks < KS; ++ks)                         \
        _Pragma("unroll") for (int t = 0; t < 4; ++t)                           \
          acc[t] = __builtin_amdgcn_mfma_scale_f32_16x16x128_f8f6f4(            \
              af[t][ks], BUF[ks], acc[t], 0, 0, 0, SC1, 0, SC1);                \
      _Pragma("unroll") for (int t = 0; t < 4; ++t)                             \
        _Pragma("unroll") for (int r = 0; r < 4; ++r)                           \
          accS[t][r] += __builtin_amdgcn_exp2f(fmaf(acc[t][r], S2, -S2));       \
    }

  for (int ch = 0; ch < NCHUNK - 1; ch += 2) {
    // Compute chunk ch from bA, then refill bA with chunk ch+2 (clamped).
    {
      f32x4 acc[4];
      #pragma unroll
      for (int t = 0; t < 4; ++t) acc[t] = (f32x4)0.0f;
      #pragma unroll
      for (int ks = 0; ks < KS; ++ks)
        #pragma unroll
        for (int t = 0; t < 4; ++t)
          acc[t] = __builtin_amdgcn_mfma_scale_f32_16x16x128_f8f6f4(
              af[t][ks], bA[ks], acc[t], 0, 0, 0, SC1, 0, SC1);
      int cn = ch + 2 < NCHUNK ? ch + 2 : NCHUNK - 1;
      const char* p = gb + (size_t)cn * 8192;
      #pragma unroll
      for (int ks = 0; ks < KS; ++ks) bA[ks] = *(const i32x8*)(p + ks * 2048);
      #pragma unroll
      for (int t = 0; t < 4; ++t)
        #pragma unroll
        for (int r = 0; r < 4; ++r)
          accS[t][r] += __builtin_amdgcn_exp2f(fmaf(acc[t][r], S2, -S2));
    }
    // Compute chunk ch+1 from bB, then refill bB with chunk ch+3 (clamped).
    {
      f32x4 acc[4];
      #pragma unroll
      for (int t = 0; t < 4; ++t) acc[t] = (f32x4)0.0f;
      #pragma unroll
      for (int ks = 0; ks < KS; ++ks)
        #pragma unroll
        for (int t = 0; t < 4; ++t)
          acc[t] = __builtin_amdgcn_mfma_scale_f32_16x16x128_f8f6f4(
              af[t][ks], bB[ks], acc[t], 0, 0, 0, SC1, 0, SC1);
      int cn = ch + 3 < NCHUNK ? ch + 3 : NCHUNK - 1;
      const char* p = gb + (size_t)cn * 8192;
      #pragma unroll
      for (int ks = 0; ks < KS; ++ks) bB[ks] = *(const i32x8*)(p + ks * 2048);
      #pragma unroll
      for (int t = 0; t < 4; ++t)
        #pragma unroll
        for (int r = 0; r < 4; ++r)
          accS[t][r] += __builtin_amdgcn_exp2f(fmaf(acc[t][r], S2, -S2));
    }
  }
  COMPUTE(bA);  // tail chunk 124 (NCHUNK odd)
  #undef COMPUTE

  // Sum over the 16 col-lanes of each group; write per-(row,split) partials.
  #pragma unroll
  for (int t = 0; t < 4; ++t)
    #pragma unroll
    for (int r = 0; r < 4; ++r) {
      float S = accS[t][r];
      #pragma unroll
      for (int m = 1; m <= 8; m <<= 1) S += __shfl_xor(S, m, 64);
      if (c == 0)
        pS[(size_t)sp * N + row0 + t * 16 + g * 4 + r] = S;
    }
}

// Merge: S over splits; swap plain label term for f32 margin term; NLL mean.
__global__ void k_merge(const float* __restrict__ pS, const float* __restrict__ coslab,
                        float* __restrict__ out) {
  int row = blockIdx.x * 256 + threadIdx.x;
  float S = 0.0f;
  #pragma unroll
  for (int s = 0; s < NSPLIT; ++s) S += pS[(size_t)s * N + row];
  float cl = coslab[row];
  float zp = SCL * cl;
  float ccl = fminf(fmaxf(cl, -1.0f + EPSC), 1.0f - EPSC);
  float zm = SCL * (ccl * COSM - sqrtf(1.0f - ccl * ccl) * SINM);
  float denom = S - __expf(zp - SCL) + __expf(zm - SCL);
  float nll = SCL + logf(denom) - zm;
  #pragma unroll
  for (int m = 1; m <= 32; m <<= 1) nll += __shfl_xor(nll, m, 64);
  __shared__ float part[4];
  if ((threadIdx.x & 63) == 0) part[threadIdx.x >> 6] = nll;
  __syncthreads();
  if (threadIdx.x == 0)
    atomicAdd(out, (part[0] + part[1] + part[2] + part[3]) * (1.0f / N));
}

__global__ void k_zero(float* out) { *out = 0.0f; }

extern "C" void kernel_launch(void* const* d_in, const int* in_sizes, int n_in,
                              void* d_out, int out_size, void* d_ws, size_t ws_size,
                              hipStream_t stream) {
  const float* x = (const float*)d_in[0];
  const float* w = (const float*)d_in[1];
  const int* labels = (const int*)d_in[2];
  float* out = (float*)d_out;

  // ws: xn8 fp8 [N*D] | wt fp8-grouped [C*D] | pS f32 [NSPLIT*N] | coslab f32 [N]
  char* xn8 = (char*)d_ws;
  char* wt = xn8 + (size_t)N * D;
  float* pS = (float*)(wt + (size_t)C * D);
  float* coslab = pS + (size_t)NSPLIT * N;

  hipLaunchKernelGGL(k_zero, dim3(1), dim3(1), 0, stream, out);
  hipLaunchKernelGGL(k_norm_x, dim3(N / 4), dim3(256), 0, stream, x, xn8);
  hipLaunchKernelGGL(k_normw_t, dim3(C / 16), dim3(256), 0, stream, w, wt);
  hipLaunchKernelGGL(k_lab, dim3(N / 4), dim3(256), 0, stream, x, w, labels, coslab);
  hipLaunchKernelGGL(k_fused, dim3(32 * NSPLIT), dim3(256), 0, stream, xn8, wt, pS);
  hipLaunchKernelGGL(k_merge, dim3(N / 256), dim3(256), 0, stream, pS, coslab, out);
}

// Round 10
// 135.066 us; speedup vs baseline: 2.0841x; 1.0425x over previous
//
#include <hip/hip_runtime.h>

// ArcMarginLoss fused: normalize -> MX-fp8 MFMA GEMM + fixed-max softmax -> NLL mean.
// N=8192, D=512, C=32000, scale=16, margin=0.2.
// R10: accumulator ping-pong. Chunk c+1's MFMAs (accQ) are independent of chunk
// c's exp epilogue (accP) -> scheduler fills matrix-pipe stalls with exp VALU.
// (R9 showed matrix pipe idle 50%: exp depended on same chunk's MFMAs and the
// 2 waves/SIMD stay phase-locked.) B-buffer shrunk to 32 regs via per-ks
// staggered refill (~550cyc prefetch distance >> ~200cyc L2 latency).

typedef __attribute__((ext_vector_type(4))) float f32x4;
typedef __attribute__((ext_vector_type(8))) int i32x8;

constexpr int N = 8192, D = 512, C = 32000;
constexpr int BM = 256;            // rows per block (4 waves x 4 tiles x 16 rows)
constexpr int GRP = 16;            // cols per chunk
constexpr int NSPLIT = 16;         // column splits of C
constexpr int CPS = C / NSPLIT;    // 2000 cols per split
constexpr int NCHUNK = CPS / GRP;  // 125 chunks
constexpr int KS = D / 128;        // 4 k-steps of K=128
constexpr float SCL = 16.0f;
constexpr float LOG2E = 1.4426950408889634f;
constexpr float S2 = SCL * LOG2E;
constexpr float COSM = 0.98006657784124163f;  // cos(0.2)
constexpr float SINM = 0.19866933079506122f;  // sin(0.2)
constexpr float EPSC = 1e-7f;
constexpr int SC1 = 0x7F7F7F7F;    // E8M0 scale bytes = 127 -> 2^0 = 1.0

// Pack 8 scaled floats -> 8 fp8 e4m3 bytes (two i32 words), hw RNE+sat.
__device__ __forceinline__ void pack8_fp8(const float* f, float sc, int& lo, int& hi) {
  lo = __builtin_amdgcn_cvt_pk_fp8_f32(f[0] * sc, f[1] * sc, 0, 0);
  lo = __builtin_amdgcn_cvt_pk_fp8_f32(f[2] * sc, f[3] * sc, lo, 1);
  hi = __builtin_amdgcn_cvt_pk_fp8_f32(f[4] * sc, f[5] * sc, 0, 0);
  hi = __builtin_amdgcn_cvt_pk_fp8_f32(f[6] * sc, f[7] * sc, hi, 1);
}

// x: one wave per row, L2-normalize, emit row-major fp8 (8 B/lane).
__global__ void k_norm_x(const float* __restrict__ in, char* __restrict__ out) {
  int w = (blockIdx.x << 2) + (threadIdx.x >> 6);
  int lane = threadIdx.x & 63;
  const float* row = in + (size_t)w * D;
  float f[8];
  *(f32x4*)&f[0] = *(const f32x4*)(row + lane * 8);
  *(f32x4*)&f[4] = *(const f32x4*)(row + lane * 8 + 4);
  float ss = 0.f;
  #pragma unroll
  for (int i = 0; i < 8; ++i) ss += f[i] * f[i];
  #pragma unroll
  for (int m = 1; m <= 32; m <<= 1) ss += __shfl_xor(ss, m, 64);
  float sc = 1.0f / fmaxf(sqrtf(ss), 1e-12f);
  int lo, hi;
  pack8_fp8(f, sc, lo, hi);
  int2 pk; pk.x = lo; pk.y = hi;
  *(int2*)(out + (size_t)w * D + lane * 8) = pk;
}

// w: one block per 16-col group; normalize 16 rows, emit fused-ready layout.
// Per 8KB group: byte addr = ks*2048 + (g*16 + col)*32 + j holds
// w[col][ks*128 + g*32 + j] (j in 0..31): each fused lane's 32B is contiguous.
__global__ void k_normw_t(const float* __restrict__ in, char* __restrict__ wt) {
  __shared__ __align__(16) char lbuf[8192];
  const int tid = threadIdx.x, wv = tid >> 6, L = tid & 63;
  const int gidx = blockIdx.x;
  #pragma unroll
  for (int t = 0; t < 4; ++t) {
    int rl = t * 4 + wv;  // 0..15 (col within group)
    const float* row = in + ((size_t)gidx * 16 + rl) * D;
    float f[8];
    *(f32x4*)&f[0] = *(const f32x4*)(row + L * 8);
    *(f32x4*)&f[4] = *(const f32x4*)(row + L * 8 + 4);
    float ss = 0.f;
    #pragma unroll
    for (int i = 0; i < 8; ++i) ss += f[i] * f[i];
    #pragma unroll
    for (int m = 1; m <= 32; m <<= 1) ss += __shfl_xor(ss, m, 64);
    float sc = 1.0f / fmaxf(sqrtf(ss), 1e-12f);
    int lo, hi;
    pack8_fp8(f, sc, lo, hi);
    // lane L covers k in [8L,8L+8): ks=L>>4, g=(L>>2)&3, j0=(L&3)*8
    int addr = (L >> 4) * 2048 + (((L >> 2) & 3) * 16 + rl) * 32 + (L & 3) * 8;
    long pk = ((long)(unsigned)hi << 32) | (unsigned)lo;
    *(long*)(lbuf + addr) = pk;
  }
  __syncthreads();
  char* outp = wt + (size_t)gidx * 8192;
  #pragma unroll
  for (int i = 0; i < 2; ++i)
    *(uint4*)(outp + i * 4096 + tid * 16) = *(const uint4*)(lbuf + i * 4096 + tid * 16);
}

// Label-column cosine in f32 (one wave per row) -> coslab[N].
__global__ void k_lab(const float* __restrict__ x, const float* __restrict__ w,
                      const int* __restrict__ labels, float* __restrict__ coslab) {
  int r = (blockIdx.x << 2) + (threadIdx.x >> 6);
  int lane = threadIdx.x & 63;
  const float* xr = x + (size_t)r * D;
  const float* wr = w + (size_t)labels[r] * D;
  f32x4 a = *(const f32x4*)(xr + lane * 8);
  f32x4 b = *(const f32x4*)(xr + lane * 8 + 4);
  f32x4 p = *(const f32x4*)(wr + lane * 8);
  f32x4 q = *(const f32x4*)(wr + lane * 8 + 4);
  float xx = a.x*a.x + a.y*a.y + a.z*a.z + a.w*a.w + b.x*b.x + b.y*b.y + b.z*b.z + b.w*b.w;
  float ww = p.x*p.x + p.y*p.y + p.z*p.z + p.w*p.w + q.x*q.x + q.y*q.y + q.z*q.z + q.w*q.w;
  float xw = a.x*p.x + a.y*p.y + a.z*p.z + a.w*p.w + b.x*q.x + b.y*q.y + b.z*q.z + b.w*q.w;
  #pragma unroll
  for (int m = 1; m <= 32; m <<= 1) {
    xx += __shfl_xor(xx, m, 64);
    ww += __shfl_xor(ww, m, 64);
    xw += __shfl_xor(xw, m, 64);
  }
  if (lane == 0)
    coslab[r] = xw / (fmaxf(sqrtf(xx), 1e-12f) * fmaxf(sqrtf(ww), 1e-12f));
}

// One chunk: 16 MFMAs into ACC, interleaved with the exp epilogue of ACCPREV
// (independent -> fills matrix-pipe stalls), per-ks staggered b refill.
#define CHUNK_STEP(ACC, ACCPREV, DOEXP, NEXTOFF)                              \
  {                                                                           \
    _Pragma("unroll")                                                         \
    for (int t = 0; t < 4; ++t) ACC[t] = (f32x4)0.0f;                         \
    _Pragma("unroll")                                                         \
    for (int ks = 0; ks < KS; ++ks) {                                         \
      _Pragma("unroll")                                                       \
      for (int t = 0; t < 4; ++t)                                             \
        ACC[t] = __builtin_amdgcn_mfma_scale_f32_16x16x128_f8f6f4(            \
            af[t][ks], b[ks], ACC[t], 0, 0, 0, SC1, 0, SC1);                  \
      if (DOEXP) {                                                            \
        _Pragma("unroll")                                                     \
        for (int r = 0; r < 4; ++r)                                           \
          accS[ks][r] +=                                                      \
              __builtin_amdgcn_exp2f(fmaf(ACCPREV[ks][r], S2, -S2));          \
      }                                                                       \
      b[ks] = *(const i32x8*)(gb + (NEXTOFF) + ks * 2048);                    \
    }                                                                         \
  }

// Fused MX-fp8 GEMM, barrier-free, acc ping-pong; B streams L2->registers.
__global__ __launch_bounds__(256, 2) void k_fused(
    const char* __restrict__ xn8, const char* __restrict__ wt,
    float* __restrict__ pS) {
  const int tid = threadIdx.x;
  const int wv = tid >> 6, lane = tid & 63;
  const int g = lane >> 4, c = lane & 15;
  const int bid = blockIdx.x;
  const int logical = (bid & 7) * 64 + (bid >> 3);  // 512 = 8*64 XCD swizzle
  const int sp = logical >> 5;          // 0..15 (2 splits per XCD = 4MB in L2)
  const int rb = logical & 31;          // 0..31
  const int row0 = rb * BM + wv * 64;   // this wave's 64 rows (4 tiles of 16)

  // 4 A-tiles fully K-resident: af[t][ks] = x[row0+t*16+c][ks*128+g*32 .. +32].
  i32x8 af[4][KS];
  #pragma unroll
  for (int t = 0; t < 4; ++t) {
    const char* xr = xn8 + (size_t)(row0 + t * 16 + c) * D + g * 32;
    #pragma unroll
    for (int ks = 0; ks < KS; ++ks) af[t][ks] = *(const i32x8*)(xr + ks * 128);
  }

  float accS[4][4];
  #pragma unroll
  for (int t = 0; t < 4; ++t)
    #pragma unroll
    for (int r = 0; r < 4; ++r) accS[t][r] = 0.0f;

  // Per-lane B base: fragment for (chunk,ks) at ch*8192 + ks*2048 + lane*32.
  const char* gb = wt + (size_t)(sp * NCHUNK) * 8192 + lane * 32;

  i32x8 b[KS];
  #pragma unroll
  for (int ks = 0; ks < KS; ++ks) b[ks] = *(const i32x8*)(gb + ks * 2048);

  f32x4 accP[4], accQ[4];

  // Prologue: chunk 0 -> accP (no exps yet); refills b <- chunk 1.
  CHUNK_STEP(accP, accQ, false, 8192)

  for (int ch = 1; ch + 1 < NCHUNK; ch += 2) {
    size_t o1 = (size_t)(ch + 1) * 8192;
    size_t o2 = (size_t)(ch + 2 < NCHUNK ? ch + 2 : NCHUNK - 1) * 8192;
    // chunk ch -> accQ, exps of accP (chunk ch-1); refill b <- chunk ch+1.
    CHUNK_STEP(accQ, accP, true, o1)
    // chunk ch+1 -> accP, exps of accQ (chunk ch); refill b <- chunk ch+2.
    CHUNK_STEP(accP, accQ, true, o2)
  }
  // Tail: exps of accP (chunk 124).
  #pragma unroll
  for (int t = 0; t < 4; ++t)
    #pragma unroll
    for (int r = 0; r < 4; ++r)
      accS[t][r] += __builtin_amdgcn_exp2f(fmaf(accP[t][r], S2, -S2));

  // Sum over the 16 col-lanes of each group; write per-(row,split) partials.
  #pragma unroll
  for (int t = 0; t < 4; ++t)
    #pragma unroll
    for (int r = 0; r < 4; ++r) {
      float S = accS[t][r];
      #pragma unroll
      for (int m = 1; m <= 8; m <<= 1) S += __shfl_xor(S, m, 64);
      if (c == 0)
        pS[(size_t)sp * N + row0 + t * 16 + g * 4 + r] = S;
    }
}
#undef CHUNK_STEP

// Merge: S over splits; swap plain label term for f32 margin term; NLL mean.
__global__ void k_merge(const float* __restrict__ pS, const float* __restrict__ coslab,
                        float* __restrict__ out) {
  int row = blockIdx.x * 256 + threadIdx.x;
  float S = 0.0f;
  #pragma unroll
  for (int s = 0; s < NSPLIT; ++s) S += pS[(size_t)s * N + row];
  float cl = coslab[row];
  float zp = SCL * cl;
  float ccl = fminf(fmaxf(cl, -1.0f + EPSC), 1.0f - EPSC);
  float zm = SCL * (ccl * COSM - sqrtf(1.0f - ccl * ccl) * SINM);
  float denom = S - __expf(zp - SCL) + __expf(zm - SCL);
  float nll = SCL + logf(denom) - zm;
  #pragma unroll
  for (int m = 1; m <= 32; m <<= 1) nll += __shfl_xor(nll, m, 64);
  __shared__ float part[4];
  if ((threadIdx.x & 63) == 0) part[threadIdx.x >> 6] = nll;
  __syncthreads();
  if (threadIdx.x == 0)
    atomicAdd(out, (part[0] + part[1] + part[2] + part[3]) * (1.0f / N));
}

__global__ void k_zero(float* out) { *out = 0.0f; }

extern "C" void kernel_launch(void* const* d_in, const int* in_sizes, int n_in,
                              void* d_out, int out_size, void* d_ws, size_t ws_size,
                              hipStream_t stream) {
  const float* x = (const float*)d_in[0];
  const float* w = (const float*)d_in[1];
  const int* labels = (const int*)d_in[2];
  float* out = (float*)d_out;

  // ws: xn8 fp8 [N*D] | wt fp8-grouped [C*D] | pS f32 [NSPLIT*N] | coslab f32 [N]
  char* xn8 = (char*)d_ws;
  char* wt = xn8 + (size_t)N * D;
  float* pS = (float*)(wt + (size_t)C * D);
  float* coslab = pS + (size_t)NSPLIT * N;

  hipLaunchKernelGGL(k_zero, dim3(1), dim3(1), 0, stream, out);
  hipLaunchKernelGGL(k_norm_x, dim3(N / 4), dim3(256), 0, stream, x, xn8);
  hipLaunchKernelGGL(k_normw_t, dim3(C / 16), dim3(256), 0, stream, w, wt);
  hipLaunchKernelGGL(k_lab, dim3(N / 4), dim3(256), 0, stream, x, w, labels, coslab);
  hipLaunchKernelGGL(k_fused, dim3(32 * NSPLIT), dim3(256), 0, stream, xn8, wt, pS);
  hipLaunchKernelGGL(k_merge, dim3(N / 256), dim3(256), 0, stream, pS, coslab, out);
}

// Round 11
// 134.383 us; speedup vs baseline: 2.0947x; 1.0051x over previous
//
#include <hip/hip_runtime.h>

// ArcMarginLoss fused: normalize -> MX-fp8 MFMA GEMM + fixed-max softmax -> NLL mean.
// N=8192, D=512, C=32000, scale=16, margin=0.2.
// R11: cut epilogue VALU (R10 showed MfmaUtil+VALUBusy=95% -> per-SIMD additive
// pipes; wall = MFMA_us + VALU_us). (a) MX scales 2^2 x 2^2 + A pre-scaled by
// 1.4427 -> MFMA emits S2*cos directly, epilogue = exp2+add only (no mul);
// (b) persistent fzero as C-in for ks=0 (no per-chunk acc zeroing);
// (c) wave-uniform pointer bump + per-lane offset VGPR (no 64b VALU addr adds).
// Correction factor e^-16 applied once in k_merge.

typedef __attribute__((ext_vector_type(4))) float f32x4;
typedef __attribute__((ext_vector_type(8))) int i32x8;

constexpr int N = 8192, D = 512, C = 32000;
constexpr int BM = 256;            // rows per block (4 waves x 4 tiles x 16 rows)
constexpr int GRP = 16;            // cols per chunk
constexpr int NSPLIT = 16;         // column splits of C
constexpr int CPS = C / NSPLIT;    // 2000 cols per split
constexpr int NCHUNK = CPS / GRP;  // 125 chunks
constexpr int KS = D / 128;        // 4 k-steps of K=128
constexpr float SCL = 16.0f;
constexpr float LOG2E = 1.4426950408889634f;
constexpr float S2 = SCL * LOG2E;              // 23.083
constexpr float COSM = 0.98006657784124163f;  // cos(0.2)
constexpr float SINM = 0.19866933079506122f;  // sin(0.2)
constexpr float EPSC = 1e-7f;
constexpr float EM16 = 1.12535174719259114e-07f;  // exp(-16)
constexpr int SCQ = 0x81818181;    // E8M0 byte 129 -> 2^2 per operand (2^4 total)

// Pack 8 scaled floats -> 8 fp8 e4m3 bytes (two i32 words), hw RNE+sat.
__device__ __forceinline__ void pack8_fp8(const float* f, float sc, int& lo, int& hi) {
  lo = __builtin_amdgcn_cvt_pk_fp8_f32(f[0] * sc, f[1] * sc, 0, 0);
  lo = __builtin_amdgcn_cvt_pk_fp8_f32(f[2] * sc, f[3] * sc, lo, 1);
  hi = __builtin_amdgcn_cvt_pk_fp8_f32(f[4] * sc, f[5] * sc, 0, 0);
  hi = __builtin_amdgcn_cvt_pk_fp8_f32(f[6] * sc, f[7] * sc, hi, 1);
}

// x: one wave per row, L2-normalize, scale by log2e (MX scale supplies 2^4),
// emit row-major fp8 (8 B/lane). Also zero-inits the output scalar (block 0).
__global__ void k_norm_x(const float* __restrict__ in, char* __restrict__ out,
                         float* __restrict__ outz) {
  if (blockIdx.x == 0 && threadIdx.x == 0) *outz = 0.0f;
  int w = (blockIdx.x << 2) + (threadIdx.x >> 6);
  int lane = threadIdx.x & 63;
  const float* row = in + (size_t)w * D;
  float f[8];
  *(f32x4*)&f[0] = *(const f32x4*)(row + lane * 8);
  *(f32x4*)&f[4] = *(const f32x4*)(row + lane * 8 + 4);
  float ss = 0.f;
  #pragma unroll
  for (int i = 0; i < 8; ++i) ss += f[i] * f[i];
  #pragma unroll
  for (int m = 1; m <= 32; m <<= 1) ss += __shfl_xor(ss, m, 64);
  float sc = LOG2E / fmaxf(sqrtf(ss), 1e-12f);
  int lo, hi;
  pack8_fp8(f, sc, lo, hi);
  int2 pk; pk.x = lo; pk.y = hi;
  *(int2*)(out + (size_t)w * D + lane * 8) = pk;
}

// w: one block per 16-col group; normalize 16 rows, emit fused-ready layout.
// Per 8KB group: byte addr = ks*2048 + (g*16 + col)*32 + j holds
// w[col][ks*128 + g*32 + j] (j in 0..31): each fused lane's 32B is contiguous.
__global__ void k_normw_t(const float* __restrict__ in, char* __restrict__ wt) {
  __shared__ __align__(16) char lbuf[8192];
  const int tid = threadIdx.x, wv = tid >> 6, L = tid & 63;
  const int gidx = blockIdx.x;
  #pragma unroll
  for (int t = 0; t < 4; ++t) {
    int rl = t * 4 + wv;  // 0..15 (col within group)
    const float* row = in + ((size_t)gidx * 16 + rl) * D;
    float f[8];
    *(f32x4*)&f[0] = *(const f32x4*)(row + L * 8);
    *(f32x4*)&f[4] = *(const f32x4*)(row + L * 8 + 4);
    float ss = 0.f;
    #pragma unroll
    for (int i = 0; i < 8; ++i) ss += f[i] * f[i];
    #pragma unroll
    for (int m = 1; m <= 32; m <<= 1) ss += __shfl_xor(ss, m, 64);
    float sc = 1.0f / fmaxf(sqrtf(ss), 1e-12f);
    int lo, hi;
    pack8_fp8(f, sc, lo, hi);
    // lane L covers k in [8L,8L+8): ks=L>>4, g=(L>>2)&3, j0=(L&3)*8
    int addr = (L >> 4) * 2048 + (((L >> 2) & 3) * 16 + rl) * 32 + (L & 3) * 8;
    long pk = ((long)(unsigned)hi << 32) | (unsigned)lo;
    *(long*)(lbuf + addr) = pk;
  }
  __syncthreads();
  char* outp = wt + (size_t)gidx * 8192;
  #pragma unroll
  for (int i = 0; i < 2; ++i)
    *(uint4*)(outp + i * 4096 + tid * 16) = *(const uint4*)(lbuf + i * 4096 + tid * 16);
}

// Label-column cosine in f32 (one wave per row) -> coslab[N].
__global__ void k_lab(const float* __restrict__ x, const float* __restrict__ w,
                      const int* __restrict__ labels, float* __restrict__ coslab) {
  int r = (blockIdx.x << 2) + (threadIdx.x >> 6);
  int lane = threadIdx.x & 63;
  const float* xr = x + (size_t)r * D;
  const float* wr = w + (size_t)labels[r] * D;
  f32x4 a = *(const f32x4*)(xr + lane * 8);
  f32x4 b = *(const f32x4*)(xr + lane * 8 + 4);
  f32x4 p = *(const f32x4*)(wr + lane * 8);
  f32x4 q = *(const f32x4*)(wr + lane * 8 + 4);
  float xx = a.x*a.x + a.y*a.y + a.z*a.z + a.w*a.w + b.x*b.x + b.y*b.y + b.z*b.z + b.w*b.w;
  float ww = p.x*p.x + p.y*p.y + p.z*p.z + p.w*p.w + q.x*q.x + q.y*q.y + q.z*q.z + q.w*q.w;
  float xw = a.x*p.x + a.y*p.y + a.z*p.z + a.w*p.w + b.x*q.x + b.y*q.y + b.z*q.z + b.w*q.w;
  #pragma unroll
  for (int m = 1; m <= 32; m <<= 1) {
    xx += __shfl_xor(xx, m, 64);
    ww += __shfl_xor(ww, m, 64);
    xw += __shfl_xor(xw, m, 64);
  }
  if (lane == 0)
    coslab[r] = xw / (fmaxf(sqrtf(xx), 1e-12f) * fmaxf(sqrtf(ww), 1e-12f));
}

// One chunk: 16 MFMAs into ACC (ks=0 seeds from fzero -> no zeroing VALU),
// exp2+add epilogue of ACCPREV interleaved, per-ks staggered b refill from
// wave-uniform base p (per-lane offset lives in loff once).
#define CHUNK_STEP(ACC, ACCPREV, DOEXP, PNEXT)                                \
  {                                                                           \
    _Pragma("unroll")                                                         \
    for (int ks = 0; ks < KS; ++ks) {                                         \
      _Pragma("unroll")                                                       \
      for (int t = 0; t < 4; ++t)                                             \
        ACC[t] = __builtin_amdgcn_mfma_scale_f32_16x16x128_f8f6f4(            \
            af[t][ks], b[ks], ks == 0 ? fzero : ACC[t], 0, 0, 0,              \
            SCQ, 0, SCQ);                                                     \
      if (DOEXP) {                                                            \
        _Pragma("unroll")                                                     \
        for (int r = 0; r < 4; ++r)                                           \
          accS[ks][r] += __builtin_amdgcn_exp2f(ACCPREV[ks][r]);              \
      }                                                                       \
      b[ks] = *(const i32x8*)((PNEXT) + loff + ks * 2048);                    \
    }                                                                         \
  }

// Fused MX-fp8 GEMM, barrier-free, acc ping-pong; B streams L2->registers.
__global__ __launch_bounds__(256, 2) void k_fused(
    const char* __restrict__ xn8, const char* __restrict__ wt,
    float* __restrict__ pS) {
  const int tid = threadIdx.x;
  const int wv = tid >> 6, lane = tid & 63;
  const int g = lane >> 4, c = lane & 15;
  const int bid = blockIdx.x;
  const int logical = (bid & 7) * 64 + (bid >> 3);  // 512 = 8*64 XCD swizzle
  const int sp = logical >> 5;          // 0..15 (2 splits per XCD = 4MB in L2)
  const int rb = logical & 31;          // 0..31
  const int row0 = rb * BM + wv * 64;   // this wave's 64 rows (4 tiles of 16)

  // 4 A-tiles fully K-resident: af[t][ks] = x[row0+t*16+c][ks*128+g*32 .. +32].
  i32x8 af[4][KS];
  #pragma unroll
  for (int t = 0; t < 4; ++t) {
    const char* xr = xn8 + (size_t)(row0 + t * 16 + c) * D + g * 32;
    #pragma unroll
    for (int ks = 0; ks < KS; ++ks) af[t][ks] = *(const i32x8*)(xr + ks * 128);
  }

  float accS[4][4];
  #pragma unroll
  for (int t = 0; t < 4; ++t)
    #pragma unroll
    for (int r = 0; r < 4; ++r) accS[t][r] = 0.0f;

  const f32x4 fzero = (f32x4)0.0f;    // persistent zero C-in for ks=0

  // Wave-uniform chunk base p; per-lane offset loff (one VGPR, set once).
  const char* p = wt + (size_t)(sp * NCHUNK) * 8192;
  const int loff = lane * 32;

  i32x8 b[KS];
  #pragma unroll
  for (int ks = 0; ks < KS; ++ks) b[ks] = *(const i32x8*)(p + loff + ks * 2048);

  f32x4 accP[4], accQ[4];

  // Prologue: chunk 0 -> accP (no exps yet); refills b <- chunk 1.
  CHUNK_STEP(accP, accQ, false, p + 8192)

  for (int ch = 1; ch + 1 < NCHUNK; ch += 2) {
    // chunk ch -> accQ, exps of accP (chunk ch-1); refill b <- chunk ch+1.
    CHUNK_STEP(accQ, accP, true, p + 2 * 8192)
    // chunk ch+1 -> accP, exps of accQ (chunk ch); refill b <- chunk ch+2 (clamped).
    CHUNK_STEP(accP, accQ, true, (ch + 2 < NCHUNK ? p + 3 * 8192 : p + 2 * 8192))
    p += 2 * 8192;
  }
  // Tail: exps of accP (chunk 124).
  #pragma unroll
  for (int t = 0; t < 4; ++t)
    #pragma unroll
    for (int r = 0; r < 4; ++r)
      accS[t][r] += __builtin_amdgcn_exp2f(accP[t][r]);

  // Sum over the 16 col-lanes of each group; write per-(row,split) partials.
  #pragma unroll
  for (int t = 0; t < 4; ++t)
    #pragma unroll
    for (int r = 0; r < 4; ++r) {
      float S = accS[t][r];
      #pragma unroll
      for (int m = 1; m <= 8; m <<= 1) S += __shfl_xor(S, m, 64);
      if (c == 0)
        pS[(size_t)sp * N + row0 + t * 16 + g * 4 + r] = S;
    }
}
#undef CHUNK_STEP

// Merge: S over splits (scaled by e^16); swap plain label term for f32 margin
// term; NLL mean.
__global__ void k_merge(const float* __restrict__ pS, const float* __restrict__ coslab,
                        float* __restrict__ out) {
  int row = blockIdx.x * 256 + threadIdx.x;
  float S = 0.0f;
  #pragma unroll
  for (int s = 0; s < NSPLIT; ++s) S += pS[(size_t)s * N + row];
  float cl = coslab[row];
  float zp = SCL * cl;
  float ccl = fminf(fmaxf(cl, -1.0f + EPSC), 1.0f - EPSC);
  float zm = SCL * (ccl * COSM - sqrtf(1.0f - ccl * ccl) * SINM);
  float denom = S * EM16 - __expf(zp - SCL) + __expf(zm - SCL);
  float nll = SCL + logf(denom) - zm;
  #pragma unroll
  for (int m = 1; m <= 32; m <<= 1) nll += __shfl_xor(nll, m, 64);
  __shared__ float part[4];
  if ((threadIdx.x & 63) == 0) part[threadIdx.x >> 6] = nll;
  __syncthreads();
  if (threadIdx.x == 0)
    atomicAdd(out, (part[0] + part[1] + part[2] + part[3]) * (1.0f / N));
}

extern "C" void kernel_launch(void* const* d_in, const int* in_sizes, int n_in,
                              void* d_out, int out_size, void* d_ws, size_t ws_size,
                              hipStream_t stream) {
  const float* x = (const float*)d_in[0];
  const float* w = (const float*)d_in[1];
  const int* labels = (const int*)d_in[2];
  float* out = (float*)d_out;

  // ws: xn8 fp8 [N*D] | wt fp8-grouped [C*D] | pS f32 [NSPLIT*N] | coslab f32 [N]
  char* xn8 = (char*)d_ws;
  char* wt = xn8 + (size_t)N * D;
  float* pS = (float*)(wt + (size_t)C * D);
  float* coslab = pS + (size_t)NSPLIT * N;

  hipLaunchKernelGGL(k_norm_x, dim3(N / 4), dim3(256), 0, stream, x, xn8, out);
  hipLaunchKernelGGL(k_normw_t, dim3(C / 16), dim3(256), 0, stream, w, wt);
  hipLaunchKernelGGL(k_lab, dim3(N / 4), dim3(256), 0, stream, x, w, labels, coslab);
  hipLaunchKernelGGL(k_fused, dim3(32 * NSPLIT), dim3(256), 0, stream, xn8, wt, pS);
  hipLaunchKernelGGL(k_merge, dim3(N / 256), dim3(256), 0, stream, pS, coslab, out);
}